// Round 1
// 346.031 us; speedup vs baseline: 1.0177x; 1.0177x over previous
//
#include <hip/hip_runtime.h>
#include <math.h>

#define H 8192
#define NSPLIT 64
#define NSEG 32          // compaction segments (k1 blocks)
#define SEGSZ 256        // columns per compaction segment
#define XSTRIPE 1024     // k2 column stripe per block.x

typedef float floatx4 __attribute__((ext_vector_type(4)));

// ws layout (float index):
//   vals    : [0, 8192)            compacted h1 values
//   rows    : [8192, 16384)        compacted h1 row offsets (int, premultiplied by H)
//   cnt     : [16384, 16416)       per-segment counts (32 ints)
//   pen     : [16416, 16424)       h2 @ W3 accumulator (8 floats)
//   ctr     : [16424]              k3 completion counter (int)
//   partial : [16432, 16432+NSPLIT*H)
#define WS_VALS 0
#define WS_ROWS 8192
#define WS_CNT 16384
#define WS_PEN 16416
#define WS_CTR 16424
#define WS_PARTIAL 16432

// ---- k1: h1 = relu(state@W1 + b1); compact nonzeros per segment; zero pen/ctr ----
// 32 blocks x 64 threads, 4 cols/thread: 4x the CU coverage of the old 8-block version.
__global__ __launch_bounds__(64) void k1_h1(const float* __restrict__ state,
                      const float* __restrict__ W1,
                      const float* __restrict__ b1,
                      float* __restrict__ vals,
                      int* __restrict__ rows,
                      int* __restrict__ cnt,
                      float* __restrict__ pen,
                      int* __restrict__ ctr) {
    __shared__ float sv[SEGSZ];
    __shared__ int   sr[SEGSZ];
    __shared__ int   scnt;
    int tid = threadIdx.x;
    if (tid == 0) scnt = 0;
    if (blockIdx.x == 0) {
        if (tid < 8) pen[tid] = 0.0f;     // zero pen for k3's atomics
        if (tid == 8) *ctr = 0;           // zero completion counter (ws is poisoned)
    }
    __syncthreads();

    int j = blockIdx.x * SEGSZ + tid * 4;
    float4 acc = *(const float4*)(b1 + j);
    #pragma unroll
    for (int i = 0; i < 42; ++i) {
        float s = state[i];
        float4 w = *(const float4*)(W1 + (size_t)i * H + j);
        acc.x = fmaf(s, w.x, acc.x);
        acc.y = fmaf(s, w.y, acc.y);
        acc.z = fmaf(s, w.z, acc.z);
        acc.w = fmaf(s, w.w, acc.w);
    }
    float v[4] = { fmaxf(acc.x, 0.f), fmaxf(acc.y, 0.f),
                   fmaxf(acc.z, 0.f), fmaxf(acc.w, 0.f) };
    #pragma unroll
    for (int c = 0; c < 4; ++c) {
        if (v[c] > 0.0f) {
            int p = atomicAdd(&scnt, 1);   // LDS atomic
            sv[p] = v[c];
            sr[p] = (j + c) * H;           // premultiplied row offset (fits: < 2^26)
        }
    }
    __syncthreads();
    int n = scnt;
    if (tid == 0) cnt[blockIdx.x] = n;
    int base = blockIdx.x * SEGSZ;
    for (int p = tid; p < n; p += 64) {
        vals[base + p] = sv[p];
        rows[base + p] = sr[p];
    }
}

// ---- k2: sparse split-K GEMV over W2 (only nonzero h1 rows) -> partials ----
// The block's (val,row) chunk is staged into LDS once, so the hot loop is
// LDS-broadcast -> nontemporal float4 stream: no global latency in the address chain.
__global__ __launch_bounds__(256) void k2_partial(
        const float* __restrict__ W2,
        const float* __restrict__ vals,
        const int* __restrict__ rows,
        const int* __restrict__ cnt,
        float* __restrict__ partial) {
    __shared__ float sval[128];   // chunk = ceil(total/NSPLIT) <= ceil(8192/64) = 128
    __shared__ int   srow[128];
    int tid = threadIdx.x;

    // prefix of the 32 segment counts (wave-uniform; compile-time indexed)
    int pre[NSEG + 1];
    pre[0] = 0;
    #pragma unroll
    for (int b = 0; b < NSEG; ++b) pre[b + 1] = pre[b] + cnt[b];
    int total = pre[NSEG];
    int chunk = (total + NSPLIT - 1) / NSPLIT;
    int glo = blockIdx.y * chunk;
    int ghi = min(glo + chunk, total);
    int n = (ghi > glo) ? (ghi - glo) : 0;

    // stage this block's chunk into LDS (global pos -> segment-local slot,
    // fully unrolled so pre[] stays in registers)
    if (tid < n) {
        int p = glo + tid;
        int src = 0;
        #pragma unroll
        for (int b = 0; b < NSEG; ++b) {
            if (p >= pre[b] && p < pre[b + 1]) src = p - pre[b] + b * SEGSZ;
        }
        sval[tid] = vals[src];
        srow[tid] = rows[src];
    }
    __syncthreads();

    int j = blockIdx.x * XSTRIPE + tid * 4;   // column (float4)
    const float* wbase = W2 + j;
    floatx4 acc = (floatx4)0.0f;
    #pragma unroll 8
    for (int i = 0; i < n; ++i) {
        float s  = sval[i];                   // LDS broadcast
        int roff = srow[i];                   // premultiplied r*H
        // stream W2 with non-temporal hint: each byte is used exactly once
        floatx4 w = __builtin_nontemporal_load((const floatx4*)(wbase + roff));
        acc.x = fmaf(s, w.x, acc.x);
        acc.y = fmaf(s, w.y, acc.y);
        acc.z = fmaf(s, w.z, acc.z);
        acc.w = fmaf(s, w.w, acc.w);
    }
    *(floatx4*)(partial + (size_t)blockIdx.y * H + j) = acc;
}

// ---- k3: h2 = relu(sum partials + b2); pen += h2 @ W3 (atomic);
//          last block finalizes value + masked softmax (fused old k4) ----
__global__ __launch_bounds__(256) void k3_reduce(const float* __restrict__ partial,
                          const float* __restrict__ b2,
                          const float* __restrict__ W3,
                          float* __restrict__ pen,
                          int* __restrict__ ctr,
                          const float* __restrict__ b3,
                          const float* __restrict__ state,
                          float* __restrict__ out) {
    int tid = threadIdx.x;
    int j = blockIdx.x * 256 + tid;           // one column per thread
    float acc = b2[j];
    #pragma unroll 8
    for (int s = 0; s < NSPLIT; ++s)
        acc += __builtin_nontemporal_load(partial + (size_t)s * H + j);
    float h = fmaxf(acc, 0.0f);

    float4 w0 = *(const float4*)(W3 + (size_t)j * 8);
    float4 w1 = *(const float4*)(W3 + (size_t)j * 8 + 4);
    float a[8] = { h * w0.x, h * w0.y, h * w0.z, h * w0.w,
                   h * w1.x, h * w1.y, h * w1.z, h * w1.w };

    #pragma unroll
    for (int off = 32; off > 0; off >>= 1) {
        #pragma unroll
        for (int k = 0; k < 8; ++k) a[k] += __shfl_down(a[k], off);
    }
    if ((tid & 63) == 0) {
        #pragma unroll
        for (int k = 0; k < 8; ++k) atomicAdd(&pen[k], a[k]);
    }

    // completion: __syncthreads drains every wave's outstanding atomics
    // (compiler emits s_waitcnt vmcnt(0) before s_barrier), then thread 0
    // publishes via device-scope counter; the last block finalizes.
    __syncthreads();
    if (tid == 0) {
        __threadfence();
        if (atomicAdd(ctr, 1) == (int)gridDim.x - 1) {
            float p8[8];
            #pragma unroll
            for (int k = 0; k < 8; ++k)
                p8[k] = atomicAdd(&pen[k], 0.0f) + b3[k];   // coherent RMW read
            out[0] = p8[7];                                  // value
            bool legal[7];
            float m = -INFINITY;
            for (int i = 0; i < 7; ++i) {
                legal[i] = (state[i] == 0.0f);
                if (legal[i] && p8[i] > m) m = p8[i];
            }
            float e[7], sum = 0.0f;
            for (int i = 0; i < 7; ++i) {
                e[i] = legal[i] ? expf(p8[i] - m) : 0.0f;
                sum += e[i];
            }
            float inv = 1.0f / sum;
            for (int i = 0; i < 7; ++i) out[1 + i] = e[i] * inv;
        }
    }
}

extern "C" void kernel_launch(void* const* d_in, const int* in_sizes, int n_in,
                              void* d_out, int out_size, void* d_ws, size_t ws_size,
                              hipStream_t stream) {
    const float* state = (const float*)d_in[0];
    const float* W1    = (const float*)d_in[1];
    const float* b1    = (const float*)d_in[2];
    const float* W2    = (const float*)d_in[3];
    const float* b2    = (const float*)d_in[4];
    const float* W3    = (const float*)d_in[5];
    const float* b3    = (const float*)d_in[6];
    float* out = (float*)d_out;

    float* ws      = (float*)d_ws;
    float* vals    = ws + WS_VALS;
    int*   rows    = (int*)(ws + WS_ROWS);
    int*   cnt     = (int*)(ws + WS_CNT);
    float* pen     = ws + WS_PEN;
    int*   ctr     = (int*)(ws + WS_CTR);
    float* partial = ws + WS_PARTIAL;

    hipLaunchKernelGGL(k1_h1, dim3(NSEG), dim3(64), 0, stream,
                       state, W1, b1, vals, rows, cnt, pen, ctr);
    hipLaunchKernelGGL(k2_partial, dim3(H / XSTRIPE, NSPLIT), dim3(256), 0, stream,
                       W2, vals, rows, cnt, partial);
    hipLaunchKernelGGL(k3_reduce, dim3(H / 256), dim3(256), 0, stream,
                       partial, b2, W3, pen, ctr, b3, state, out);
}